// Round 6
// baseline (450.763 us; speedup 1.0000x reference)
//
#include <hip/hip_runtime.h>
#include <cstdint>
#include <cstddef>

#define B_   2
#define S_   2048
#define H_   16
#define D_   128
#define HID_ 2048

typedef __bf16 bf16;
typedef unsigned short u16;
typedef bf16 bf16x4 __attribute__((ext_vector_type(4)));
typedef bf16 bf16x8 __attribute__((ext_vector_type(8)));
typedef u16  u16x8  __attribute__((ext_vector_type(8)));
typedef float f32x4 __attribute__((ext_vector_type(4)));

__device__ unsigned g_work;   // work-stealing counter; zeroed by k_tables each launch

__device__ __forceinline__ f32x4 mfma16(bf16x8 a, bf16x8 b, f32x4 c){
  return __builtin_amdgcn_mfma_f32_16x16x32_bf16(a, b, c, 0, 0, 0);
}

__device__ __forceinline__ void gload_lds16(const void* g, void* l){
  __builtin_amdgcn_global_load_lds((const __attribute__((address_space(1))) void*)g,
                                   (__attribute__((address_space(3))) void*)l, 16, 0, 0);
}

template<int N>
__device__ __forceinline__ void wait_vm(){
  if constexpr (N == 0) asm volatile("s_waitcnt vmcnt(0)" ::: "memory");
  else if constexpr (N == 3) asm volatile("s_waitcnt vmcnt(3)" ::: "memory");
  else asm volatile("s_waitcnt vmcnt(4)" ::: "memory");
}

__device__ __forceinline__ void bar_lgkm(){   // drain LDS reads, then barrier (NO vmcnt drain)
  asm volatile("s_waitcnt lgkmcnt(0)" ::: "memory");
  __builtin_amdgcn_s_barrier();
}
__device__ __forceinline__ void bar_full(){   // drain everything, then barrier
  asm volatile("s_waitcnt vmcnt(0) lgkmcnt(0)" ::: "memory");
  __builtin_amdgcn_s_barrier();
}

// ---------------- RoPE tables: cos/sin [S][64] fp32 (+ work counter reset) ----------------
__global__ void k_tables(float* __restrict__ cosT, float* __restrict__ sinT){
  if (blockIdx.x == 0 && threadIdx.x == 0) g_work = 0u;
  int id = blockIdx.x*256 + threadIdx.x;      // S*64 = 131072 exact
  int p = id >> 6, i = id & 63;
  double f = (double)p * pow(10000.0, -(double)i/64.0);
  cosT[id] = (float)cos(f);
  sinT[id] = (float)sin(f);
}

// ---------------- fused fp32 -> bf16 converts (6 segments in one dispatch) ----------------
__global__ void k_cvt_all(const float* __restrict__ a0, bf16* __restrict__ o0,
                          const float* __restrict__ a1, bf16* __restrict__ o1,
                          const float* __restrict__ w0, bf16* __restrict__ q0,
                          const float* __restrict__ w1, bf16* __restrict__ q1,
                          const float* __restrict__ w2, bf16* __restrict__ q2,
                          const float* __restrict__ w3, bf16* __restrict__ q3){
  const float* src; bf16* dst; int n4;
  switch (blockIdx.y){
    case 0: src = a0; dst = o0; n4 = 2097152; break;
    case 1: src = a1; dst = o1; n4 = 2097152; break;
    case 2: src = w0; dst = q0; n4 = 1048576; break;
    case 3: src = w1; dst = q1; n4 = 1048576; break;
    case 4: src = w2; dst = q2; n4 = 1048576; break;
    default: src = w3; dst = q3; n4 = 1048576; break;
  }
  int i = blockIdx.x*256 + threadIdx.x;
  if (i >= n4) return;
  f32x4 v = *reinterpret_cast<const f32x4*>(src + (size_t)i*4);
  bf16x4 o;
  o[0]=(bf16)v[0]; o[1]=(bf16)v[1]; o[2]=(bf16)v[2]; o[3]=(bf16)v[3];
  *reinterpret_cast<bf16x4*>(dst + (size_t)i*4) = o;
}

// ---------------- hidden [B][S][HID] f32 -> hiddenT [B][HID][S] bf16 ----------------
__global__ __launch_bounds__(256) void k_transpose_cvt(const float* __restrict__ in, bf16* __restrict__ out){
  __shared__ bf16 t[64][72];
  const int tid = threadIdx.x;
  const int b = blockIdx.z, j0 = blockIdx.x*64, s0 = blockIdx.y*64;
  #pragma unroll
  for (int u0 = 0; u0 < 4; ++u0){
    int u = u0*256 + tid;
    int r = u >> 4, c4 = (u & 15)*4;
    f32x4 v = *reinterpret_cast<const f32x4*>(in + ((size_t)b*S_ + s0 + r)*HID_ + j0 + c4);
    bf16x4 o; o[0]=(bf16)v[0]; o[1]=(bf16)v[1]; o[2]=(bf16)v[2]; o[3]=(bf16)v[3];
    *reinterpret_cast<bf16x4*>(&t[r][c4]) = o;
  }
  __syncthreads();
  #pragma unroll
  for (int u0 = 0; u0 < 4; ++u0){
    int u = u0*256 + tid;
    int r = u >> 4, c4 = (u & 15)*4;    // r: j-local, c4: s-local
    bf16x4 o;
    o[0] = t[c4+0][r]; o[1] = t[c4+1][r]; o[2] = t[c4+2][r]; o[3] = t[c4+3][r];
    *reinterpret_cast<bf16x4*>(out + ((size_t)b*HID_ + j0 + r)*S_ + s0 + c4) = o;
  }
}

// ---------------- NT GEMM, 256xBN tile, 8 waves, BK=64, counted-vmcnt pipeline --------------
// C[M,N] = A[M,K]*B[N,K]^T, bf16 in, fp32 acc. Staging unit = k-half (32 cols) of one matrix,
// one unit issued per MFMA phase; entry/mid waits are vmcnt(NW) (never 0 in steady state).
// EPI 0: store bf16. EPI 1: += (1-mask[row])*hid[row,col], bf16 (batched). EPI 2: fp32.
// EPI 3: dual bf16 (n0<2048 -> Cv, else -> hid-as-bf16).
template<int EPI, int BN>
__global__ __launch_bounds__(512,2) void k_gemm2(
    const bf16* __restrict__ A, const bf16* __restrict__ Bm, void* __restrict__ Cv,
    int Kd, size_t sAz, size_t sBz, size_t sCz, int N,
    const float* __restrict__ mask, const float* __restrict__ hid)
{
  constexpr int NW = (BN == 256) ? 4 : 3;   // loads per (A-unit + B-unit)
  constexpr int MI = (BN == 256) ? 8 : 4;   // per-wave M fragments
  constexpr int MH = MI/2;
  const int tid = threadIdx.x;
  const int wid = tid >> 6, lane = tid & 63;
  const int g = lane >> 4, li = lane & 15;
  const int wm = (BN == 256) ? (wid >> 2) : (wid >> 1);
  const int wn = (BN == 256) ? (wid & 3)  : (wid & 1);
  const int mOff = wm * ((BN == 256) ? 128 : 64);
  const int nOff = wn * 64;
  const int z = blockIdx.z;
  const int m0 = blockIdx.y*256, n0 = blockIdx.x*BN;
  const bf16* Ab = A + (size_t)z*sAz + (size_t)m0*Kd;
  const bf16* Bb = Bm + (size_t)z*sBz + (size_t)n0*Kd;

  __shared__ bf16 lA[2][2][256*32];   // [buf][kh][row*32k]  64 KiB
  __shared__ bf16 lB[2][2][BN*32];    // 64 or 32 KiB

  // staging role: thread covers row rq (+128 for 2nd instr), 16B chunk cq; XOR-preswizzled src
  const int rq = tid >> 2, cq = tid & 3;
  const int csw = cq ^ ((rq >> 1) & 3);   // (row>>1)&3 invariant under row+=128

  f32x4 acc[MI][4];
  #pragma unroll
  for (int i=0;i<MI;++i)
    #pragma unroll
    for (int j=0;j<4;++j) acc[i][j] = {0.f,0.f,0.f,0.f};

  auto stA = [&](int buf, int kt, int kh){
    const bf16* s = Ab + (size_t)rq*Kd + kt*64 + kh*32 + csw*8;
    char* d = (char*)lA[buf][kh];
    gload_lds16(s, d + wid*1024);
    gload_lds16(s + (size_t)128*Kd, d + 8192 + wid*1024);
  };
  auto stB = [&](int buf, int kt, int kh){
    char* d = (char*)lB[buf][kh];
    const bf16* s = Bb + (size_t)rq*Kd + kt*64 + kh*32 + csw*8;
    if constexpr (BN == 256){
      gload_lds16(s, d + wid*1024);
      gload_lds16(s + (size_t)128*Kd, d + 8192 + wid*1024);
    } else {
      gload_lds16(s, d + wid*1024);   // 128 rows = 1 instr/thread
    }
  };
  auto rdA = [&](int buf, int kh, int i){
    int row = mOff + i*16 + li;
    int c = g ^ ((row >> 1) & 3);
    return *reinterpret_cast<const bf16x8*>((const char*)lA[buf][kh] + row*64 + c*16);
  };
  auto rdB = [&](int buf, int kh, int j){
    int row = nOff + j*16 + li;
    int c = g ^ ((row >> 1) & 3);
    return *reinterpret_cast<const bf16x8*>((const char*)lB[buf][kh] + row*64 + c*16);
  };

  const int NT = Kd >> 6;
  // prologue: stage tile 0 (4 units, 2*NW loads in flight)
  stA(0,0,0); stB(0,0,0); stA(0,0,1); stB(0,0,1);

  int cur = 0;
  for (int kt = 0; kt < NT; ++kt){
    const bool more = (kt+1 < NT);
    bf16x8 af[MH], bfr[4];

    // entry: kh0 units (oldest NW+NW in flight; newest NW = this tile's kh1) -> vmcnt(NW)
    wait_vm<NW>();
    __builtin_amdgcn_s_barrier();

    if (more) stA(cur^1, kt+1, 0);
    // phase 0: kh0, i 0..MH-1
    #pragma unroll
    for (int j=0;j<4;++j) bfr[j] = rdB(cur, 0, j);
    #pragma unroll
    for (int i=0;i<MH;++i) af[i] = rdA(cur, 0, i);
    __builtin_amdgcn_s_setprio(1);
    #pragma unroll
    for (int i=0;i<MH;++i)
      #pragma unroll
      for (int j=0;j<4;++j) acc[i][j] = mfma16(af[i], bfr[j], acc[i][j]);
    __builtin_amdgcn_s_setprio(0);

    if (more) stB(cur^1, kt+1, 0);
    // phase 1: kh0, i MH..MI-1 (reuse bfr)
    #pragma unroll
    for (int i=0;i<MH;++i) af[i] = rdA(cur, 0, MH+i);
    __builtin_amdgcn_s_setprio(1);
    #pragma unroll
    for (int i=0;i<MH;++i)
      #pragma unroll
      for (int j=0;j<4;++j) acc[MH+i][j] = mfma16(af[i], bfr[j], acc[MH+i][j]);
    __builtin_amdgcn_s_setprio(0);

    // mid: need this tile's kh1 (newest NW = next tile's kh0 units); last tile: drain
    if (more) wait_vm<NW>(); else wait_vm<0>();
    __builtin_amdgcn_s_barrier();

    if (more) stA(cur^1, kt+1, 1);
    // phase 2: kh1, i 0..MH-1
    #pragma unroll
    for (int j=0;j<4;++j) bfr[j] = rdB(cur, 1, j);
    #pragma unroll
    for (int i=0;i<MH;++i) af[i] = rdA(cur, 1, i);
    __builtin_amdgcn_s_setprio(1);
    #pragma unroll
    for (int i=0;i<MH;++i)
      #pragma unroll
      for (int j=0;j<4;++j) acc[i][j] = mfma16(af[i], bfr[j], acc[i][j]);
    __builtin_amdgcn_s_setprio(0);

    if (more) stB(cur^1, kt+1, 1);
    // phase 3: kh1, i MH..MI-1
    #pragma unroll
    for (int i=0;i<MH;++i) af[i] = rdA(cur, 1, MH+i);
    __builtin_amdgcn_s_setprio(1);
    #pragma unroll
    for (int i=0;i<MH;++i)
      #pragma unroll
      for (int j=0;j<4;++j) acc[MH+i][j] = mfma16(af[i], bfr[j], acc[MH+i][j]);
    __builtin_amdgcn_s_setprio(0);

    cur ^= 1;
  }

  #pragma unroll
  for (int i=0;i<MI;++i){
    #pragma unroll
    for (int j=0;j<4;++j){
      #pragma unroll
      for (int v=0;v<4;++v){
        int row = m0 + mOff + i*16 + g*4 + v;
        int col = n0 + nOff + j*16 + li;
        float x = acc[i][j][v];
        if (EPI == 1){
          x += (1.f - mask[z*S_ + row]) * hid[((size_t)z*S_ + row)*HID_ + col];
          ((bf16*)Cv)[(size_t)z*sCz + (size_t)row*N + col] = (bf16)x;
        } else if (EPI == 0){
          ((bf16*)Cv)[(size_t)row*N + col] = (bf16)x;
        } else if (EPI == 2){
          ((float*)Cv)[(size_t)row*N + col] = x;
        } else {  // EPI 3: dual output, block-uniform split at col 2048
          if (n0 < 2048) ((bf16*)Cv)[(size_t)row*2048 + col] = (bf16)x;
          else ((bf16*)(void*)hid)[(size_t)row*2048 + col - 2048] = (bf16)x;
        }
      }
    }
  }
}

// ---------------- RoPE in place on [B,S,H,D] bf16 ----------------
__global__ void k_rope(bf16* __restrict__ X, const float* __restrict__ cosT,
                       const float* __restrict__ sinT, const int* __restrict__ pos){
  int id = blockIdx.x*256 + threadIdx.x;   // B*S*H*16 = 1048576 exact
  int d4 = (id & 15)*4;
  int h  = (id >> 4) & 15;
  int s  = (id >> 8) & 2047;
  int b  = id >> 19;
  int p = pos ? pos[b*S_ + s] : s;
  size_t base = (((size_t)b*S_ + s)*H_ + h)*D_ + d4;
  f32x4 c  = *reinterpret_cast<const f32x4*>(cosT + (size_t)p*64 + d4);
  f32x4 sn = *reinterpret_cast<const f32x4*>(sinT + (size_t)p*64 + d4);
  bf16x4 x1 = *reinterpret_cast<bf16x4*>(X + base);
  bf16x4 x2 = *reinterpret_cast<bf16x4*>(X + base + 64);
  bf16x4 o1, o2;
  #pragma unroll
  for (int i=0;i<4;++i){
    float a = (float)x1[i], bb = (float)x2[i];
    o1[i] = (bf16)(a*c[i] - bb*sn[i]);
    o2[i] = (bf16)(bb*c[i] + a*sn[i]);
  }
  *reinterpret_cast<bf16x4*>(X + base) = o1;
  *reinterpret_cast<bf16x4*>(X + base + 64) = o2;
}

// ---------------- causal flash attention: persistent, pipelined, kv-split ----------------
// 512 persistent blocks (2/CU), 4 waves x 32 q-rows = 128-row q-tiles, kv tile 64.
// Items: A) unsplit qx 10..8  B) split halves qx 15..11  C) unsplit qx 7..0. (672 items)
__global__ __launch_bounds__(256,2) void k_flash(const bf16* __restrict__ Q, const bf16* __restrict__ K,
                                                 const bf16* __restrict__ V, bf16* __restrict__ O,
                                                 float* __restrict__ OP, float* __restrict__ ML)
{
  const int tid = threadIdx.x;
  const int wid = tid >> 6, lane = tid & 63;
  const int g = lane >> 4, li = lane & 15;

  __shared__ bf16 Klds[2][64*128];    // double-buffered K, source chunk-XOR swizzled
  __shared__ char VtB[128*128];       // V^T [d][kv] bf16, XOR-swizzled 16B chunks
  __shared__ bf16 Plds[4][32*72];     // per-wave P (32 rows x 64 cols, pad 72 for 16B align)
  __shared__ int s_item;

  const int dc0 = tid & 15, kvp0 = tid >> 4;       // V-staging roles: unit0 kv rows [2*kvp0, +1]
  const int kvp1 = kvp0 + 16;                      // unit1 kv rows [2*kvp1, +1]

  for (;;) {
    if (tid == 0) s_item = (int)atomicAdd(&g_work, 1u);
    __syncthreads();
    const int w = s_item;
    if (w >= 672) return;

    int qx, bh, part, t0, t1;
    if (w < 96)       { qx = 10 - (w >> 5);  bh = w & 31;  part = -1; t0 = 0; t1 = 2*qx + 2; }
    else if (w < 416) { int u = w - 96;  qx = 15 - (u >> 6); int r = u & 63; bh = r >> 1; part = r & 1;
                        int nt = 2*qx + 2, mid = nt >> 1; t0 = part ? mid : 0; t1 = part ? nt : mid; }
    else              { int u = w - 416; qx = 7 - (u >> 5);  bh = u & 31;  part = -1; t0 = 0; t1 = 2*qx + 2; }

    const int qb = qx * 128;
    const size_t headoff = ((size_t)(bh >> 4)*S_*H_ + (bh & 15))*D_;
    const bf16* Kh = K + headoff;
    const u16*  Vh = (const u16*)(V + headoff);

    // Q fragments: 2 row-blocks of 16
    bf16x8 qf[2][4];
    #pragma unroll
    for (int rb=0;rb<2;++rb){
      const bf16* Qp = Q + headoff + (size_t)(qb + wid*32 + rb*16 + li)*H_*D_;
      #pragma unroll
      for (int kc=0;kc<4;++kc)
        qf[rb][kc] = *reinterpret_cast<const bf16x8*>(Qp + kc*32 + g*8);
    }

    float mrun[2][4], lrun[2][4];
    f32x4 acc[2][8];
    #pragma unroll
    for (int rb=0;rb<2;++rb){
      #pragma unroll
      for (int v=0;v<4;++v){ mrun[rb][v] = -1e30f; lrun[rb][v] = 0.f; }
      #pragma unroll
      for (int fn=0;fn<8;++fn) acc[rb][fn] = {0.f,0.f,0.f,0.f};
    }

    u16x8 vp[4];
    auto stageK = [&](int buf, int t){
      #pragma unroll
      for (int j=0;j<4;++j){
        int ci = j*256 + tid;
        int r = ci >> 4, cb = ci & 15;
        const char* src = (const char*)(Kh + (size_t)(t*64 + r)*H_*D_) + ((cb ^ (r & 7)) * 16);
        gload_lds16(src, (char*)Klds[buf] + (j*256 + wid*64)*16);
      }
    };
    auto loadV = [&](int t){
      const u16* s0p = Vh + (size_t)(t*64 + kvp0*2)*H_*D_ + dc0*8;
      const u16* s1p = Vh + (size_t)(t*64 + kvp1*2)*H_*D_ + dc0*8;
      vp[0] = *reinterpret_cast<const u16x8*>(s0p);
      vp[1] = *reinterpret_cast<const u16x8*>(s0p + H_*D_);
      vp[2] = *reinterpret_cast<const u16x8*>(s1p);
      vp[3] = *reinterpret_cast<const u16x8*>(s1p + H_*D_);
    };
    auto writeVtB = [&](){
      #pragma unroll
      for (int j=0;j<2;++j){
        int kvp = j ? kvp1 : kvp0;
        #pragma unroll
        for (int e=0;e<8;++e){
          int r = dc0*8 + e;
          int swz = (r ^ (r >> 3)) & 7;
          int addr = r*128 + (((kvp >> 2) ^ swz) << 4) + ((kvp << 2) & 12);
          *reinterpret_cast<uint32_t*>(VtB + addr) =
              (uint32_t)vp[j*2+0][e] | ((uint32_t)vp[j*2+1][e] << 16);
        }
      }
    };

    // prologue: stage tile t0
    stageK(0, t0);
    loadV(t0);
    writeVtB();
    bar_full();

    int cur = 0;
    for (int t=t0; t<t1; ++t){
      const bool more = (t+1 < t1);
      if (more){ stageK(cur^1, t+1); loadV(t+1); }   // overlapped with this tile's compute

      // ---- QK^T: wave computes 32 rows x 64 cols ----
      f32x4 sc[2][4];
      #pragma unroll
      for (int fc=0;fc<4;++fc){
        int r = fc*16 + li;
        bf16x8 kf[4];
        #pragma unroll
        for (int kc=0;kc<4;++kc)
          kf[kc] = *reinterpret_cast<const bf16x8*>((const char*)Klds[cur] + r*256 + (((4*kc + g) ^ (r & 7))*16));
        __builtin_amdgcn_s_setprio(1);
        #pragma unroll
        for (int rb=0;rb<2;++rb){
          f32x4 s = {0.f,0.f,0.f,0.f};
          #pragma unroll
          for (int kc=0;kc<4;++kc)
            s = mfma16(qf[rb][kc], kf[kc], s);
          sc[rb][fc] = s;
        }
        __builtin_amdgcn_s_setprio(0);
      }

      // ---- scale (+ causal mask on the two diagonal tiles) ----
      const float scale = 0.08838834764831845f;  // 1/sqrt(128)
      const int c0 = t*64;
      if (t >= 2*qx){
        #pragma unroll
        for (int rb=0;rb<2;++rb){
          const int rowg = qb + wid*32 + rb*16 + g*4;
          #pragma unroll
          for (int fc=0;fc<4;++fc){
            int col = c0 + fc*16 + li;
            #pragma unroll
            for (int v=0;v<4;++v){
              float s = sc[rb][fc][v] * scale;
              sc[rb][fc][v] = (col > rowg + v) ? -1e30f : s;
            }
          }
        }
      } else {
        #pragma unroll
        for (int rb=0;rb<2;++rb)
          #pragma unroll
          for (int fc=0;fc<4;++fc)
            #pragma unroll
            for (int v=0;v<4;++v)
              sc[rb][fc][v] *= scale;
      }

      // ---- online softmax with defer-max (THR=8), per row-block ----
      #pragma unroll
      for (int rb=0;rb<2;++rb){
        float tm[4];
        #pragma unroll
        for (int v=0;v<4;++v){
          float m2 = fmaxf(fmaxf(sc[rb][0][v], sc[rb][1][v]), fmaxf(sc[rb][2][v], sc[rb][3][v]));
          m2 = fmaxf(m2, __shfl_xor(m2, 1));
          m2 = fmaxf(m2, __shfl_xor(m2, 2));
          m2 = fmaxf(m2, __shfl_xor(m2, 4));
          m2 = fmaxf(m2, __shfl_xor(m2, 8));
          tm[v] = m2;
        }
        bool need = false;
        #pragma unroll
        for (int v=0;v<4;++v) need = need || (tm[v] > mrun[rb][v] + 8.f);
        if (__any(need)){
          float al[4];
          #pragma unroll
          for (int v=0;v<4;++v){
            float mnew = fmaxf(mrun[rb][v], tm[v]);
            al[v] = __expf(mrun[rb][v] - mnew);
            mrun[rb][v] = mnew;
            lrun[rb][v] *= al[v];
          }
          #pragma unroll
          for (int fn=0;fn<8;++fn)
            #pragma unroll
            for (int v=0;v<4;++v) acc[rb][fn][v] *= al[v];
        }
        float rs[4] = {0.f,0.f,0.f,0.f};
        #pragma unroll
        for (int fc=0;fc<4;++fc){
          #pragma unroll
          for (int v=0;v<4;++v){
            float p = __expf(sc[rb][fc][v] - mrun[rb][v]);
            rs[v] += p;
            Plds[wid][(rb*16 + g*4 + v)*72 + fc*16 + li] = (bf16)p;
          }
        }
        #pragma unroll
        for (int v=0;v<4;++v){
          float r = rs[v];
          r += __shfl_xor(r, 1); r += __shfl_xor(r, 2);
          r += __shfl_xor(r, 4); r += __shfl_xor(r, 8);
          lrun[rb][v] += r;
        }
      }

      // ---- PV: O[32 x 128] += P[32 x 64] * V[64 x 128] ----
      bf16x8 pa[2][2];
      #pragma unroll
      for (int rb=0;rb<2;++rb)
        #pragma unroll
        for (int kc=0;kc<2;++kc)
          pa[rb][kc] = *reinterpret_cast<const bf16x8*>(&Plds[wid][(rb*16 + li)*72 + kc*32 + g*8]);
      #pragma unroll
      for (int fn=0;fn<8;++fn){
        int r = fn*16 + li;
        int swz = (r ^ (r >> 3)) & 7;
        bf16x8 bv[2];
        #pragma unroll
        for (int kc=0;kc<2;++kc)
          bv[kc] = *reinterpret_cast<const bf16x8*>(VtB + r*128 + (((kc*4 + g) ^ swz) << 4));
        __builtin_amdgcn_s_setprio(1);
        #pragma unroll
        for (int rb=0;rb<2;++rb)
          #pragma unroll
          for (int kc=0;kc<2;++kc)
            acc[rb][fn] = mfma16(pa[rb][kc], bv[kc], acc[rb][fn]);
        __builtin_amdgcn_s_setprio(0);
      }

      if (more){
        bar_lgkm();        // all waves done reading VtB (LDS reads drained), no vmcnt drain
        writeVtB();        // commit next tile's V
      }
      bar_full();          // drains K-DMA issued ~1 tile ago + V ds_writes
      cur ^= 1;
    }

    // ---- epilogue ----
    if (part < 0){
      #pragma unroll
      for (int rb=0;rb<2;++rb){
        #pragma unroll
        for (int v=0;v<4;++v){
          float inv = 1.f / lrun[rb][v];
          int row = qb + wid*32 + rb*16 + g*4 + v;
          bf16* dst = O + headoff + (size_t)row*H_*D_ + li;
          #pragma unroll
          for (int fn=0;fn<8;++fn)
            dst[fn*16] = (bf16)(acc[rb][fn][v] * inv);
        }
      }
    } else {
      const int sidx = (15 - qx)*64 + (bh << 1) + part;
      float* Od = OP + (size_t)sidx*128*128;
      #pragma unroll
      for (int rb=0;rb<2;++rb){
        #pragma unroll
        for (int v=0;v<4;++v){
          int rl = wid*32 + rb*16 + g*4 + v;
          #pragma unroll
          for (int fn=0;fn<8;++fn)
            Od[rl*128 + fn*16 + li] = acc[rb][fn][v];
          if (li == 0){
            ML[(size_t)sidx*256 + rl*2 + 0] = mrun[rb][v];
            ML[(size_t)sidx*256 + rl*2 + 1] = lrun[rb][v];
          }
        }
      }
    }
  }
}

// ---------------- merge split-kv partials into O ----------------
__global__ __launch_bounds__(256) void k_merge(const float* __restrict__ OP, const float* __restrict__ ML,
                                               bf16* __restrict__ O){
  const int pair = blockIdx.x;        // 160 pairs: qx 15..11 x 32 bh
  const int qi = pair >> 5;           // 0..4 -> qx = 15-qi
  const int qx = 15 - qi;
  const int bh = pair & 31;
  const int s0 = qi*64 + (bh << 1), s1 = s0 + 1;
  const int b = bh >> 4, h = bh & 15;
  const int qb = qx * 128;
  const int row = threadIdx.x >> 1;           // 0..127
  const int cseg = (threadIdx.x & 1) * 64;    // 64 cols

  float m0 = ML[(size_t)s0*256 + row*2], l0 = ML[(size_t)s0*256 + row*2 + 1];
  float m1 = ML[(size_t)s1*256 + row*2], l1 = ML[(size_t)s1*256 + row*2 + 1];
  float m = fmaxf(m0, m1);
  float e0 = __expf(m0 - m), e1 = __expf(m1 - m);
  float inv = 1.f / (l0*e0 + l1*e1);
  const float* O0 = OP + ((size_t)s0*128 + row)*128 + cseg;
  const float* O1 = OP + ((size_t)s1*128 + row)*128 + cseg;
  bf16* dst = O + (((size_t)b*S_ + qb + row)*H_ + h)*D_ + cseg;
  #pragma unroll
  for (int c=0; c<64; c+=4){
    f32x4 a = *reinterpret_cast<const f32x4*>(O0 + c);
    f32x4 bb = *reinterpret_cast<const f32x4*>(O1 + c);
    bf16x4 o;
    #pragma unroll
    for (int i=0;i<4;++i) o[i] = (bf16)((a[i]*e0 + bb[i]*e1) * inv);
    *reinterpret_cast<bf16x4*>(dst + c) = o;
  }
}

extern "C" void kernel_launch(void* const* d_in, const int* in_sizes, int n_in,
                              void* d_out, int out_size, void* d_ws, size_t ws_size,
                              hipStream_t stream)
{
  (void)in_sizes; (void)n_in; (void)out_size; (void)ws_size;
  const float* hid   = (const float*)d_in[0];
  const float* smask = (const float*)d_in[1];
  const float* samat = (const float*)d_in[2];
  const int*   pos   = (const int*)d_in[4];
  const float* Wq = (const float*)d_in[5];
  const float* Wk = (const float*)d_in[6];
  const float* Wv = (const float*)d_in[7];
  const float* Wo = (const float*)d_in[8];
  float* out = (float*)d_out;
  char* ws = (char*)d_ws;

  const size_t SZ_TAB = (size_t)S_*64*4;        // 512 KB per table
  const size_t SZ_BSH = (size_t)B_*S_*HID_*2;   // 16 MB bf16 [B,S,HID]
  float* cosT = (float*)(ws);
  float* sinT = (float*)(ws + SZ_TAB);
  bf16* buf1 = (bf16*)(ws + 2*SZ_TAB);                 // hidden_bf -> v
  bf16* buf2 = (bf16*)(ws + 2*SZ_TAB + 1*SZ_BSH);      // hiddenT  -> k
  bf16* buf3 = (bf16*)(ws + 2*SZ_TAB + 2*SZ_BSH);      // samat_bf -> q
  bf16* buf4 = (bf16*)(ws + 2*SZ_TAB + 3*SZ_BSH);      // hm -> attention O
  bf16* Wqb = (bf16*)(ws + 2*SZ_TAB + 4*SZ_BSH);
  bf16* Wkb = Wqb + (size_t)HID_*HID_;
  bf16* Wvb = Wkb + (size_t)HID_*HID_;
  bf16* Wob = Wvb + (size_t)HID_*HID_;
  // flash split-kv partials alias the (dead-after-GEMM) Wq/Wk/Wv region: 21.3 MB <= 24 MB
  float* OP = (float*)Wqb;
  float* ML = OP + (size_t)320*128*128;

  k_tables<<<512,256,0,stream>>>(cosT, sinT);
  k_cvt_all<<<dim3(8192,6),256,0,stream>>>(hid, buf1, samat, buf3,
                                           Wq, Wqb, Wk, Wkb, Wv, Wvb, Wo, Wob);
  k_transpose_cvt<<<dim3(32,32,2),256,0,stream>>>(hid, buf2);

  const size_t sBat = (size_t)S_*HID_;
  // G1: hm = sum_attn_mask @ hidden + (1-m)*hidden   (batched; 256x128 tiles, 16x8x2 = 256 blocks)
  k_gemm2<1,128><<<dim3(16,8,2),512,0,stream>>>(buf3, buf2, buf4, 2048, sBat, sBat, sBat, 2048, smask, hid);
  // G2: q = hidden_bf @ Wq^T   (256x128 tiles, 16x16 = 256 blocks)
  k_gemm2<0,128><<<dim3(16,16,1),512,0,stream>>>(buf1, Wqb, buf3, 2048, 0,0,0, 2048, nullptr, nullptr);
  k_rope<<<4096,256,0,stream>>>(buf3, cosT, sinT, pos);
  // G3+G4 fused: [k|v] = hm @ [Wk|Wv]^T  (256x256 tiles, 16x16 = 256 blocks, dual output)
  k_gemm2<3,256><<<dim3(16,16,1),512,0,stream>>>(buf4, Wkb, buf2, 2048, 0,0,0, 4096, nullptr, (const float*)buf1);
  k_rope<<<4096,256,0,stream>>>(buf2, cosT, sinT, nullptr);
  // attention: O -> buf4 (hm dead); split partials -> OP/ML
  k_flash<<<dim3(512),256,0,stream>>>(buf3, buf2, buf1, buf4, OP, ML);
  k_merge<<<dim3(160),256,0,stream>>>(OP, ML, buf4);
  // G5: out = O @ Wo^T -> fp32  (256x128 tiles, 16x16 = 256 blocks)
  k_gemm2<2,128><<<dim3(16,16,1),512,0,stream>>>(buf4, Wob, out, 2048, 0,0,0, 2048, nullptr, nullptr);
}

// Round 7
// 413.823 us; speedup vs baseline: 1.0893x; 1.0893x over previous
//
#include <hip/hip_runtime.h>
#include <cstdint>
#include <cstddef>

#define B_   2
#define S_   2048
#define H_   16
#define D_   128
#define HID_ 2048

typedef __bf16 bf16;
typedef unsigned short u16;
typedef bf16 bf16x4 __attribute__((ext_vector_type(4)));
typedef bf16 bf16x8 __attribute__((ext_vector_type(8)));
typedef u16  u16x8  __attribute__((ext_vector_type(8)));
typedef float f32x4 __attribute__((ext_vector_type(4)));

__device__ unsigned g_work;   // work-stealing counter; zeroed by k_tables each launch

__device__ __forceinline__ f32x4 mfma16(bf16x8 a, bf16x8 b, f32x4 c){
  return __builtin_amdgcn_mfma_f32_16x16x32_bf16(a, b, c, 0, 0, 0);
}

__device__ __forceinline__ void gload_lds16(const void* g, void* l){
  __builtin_amdgcn_global_load_lds((const __attribute__((address_space(1))) void*)g,
                                   (__attribute__((address_space(3))) void*)l, 16, 0, 0);
}

__device__ __forceinline__ void bar_lgkm(){   // drain LDS reads, then barrier (NO vmcnt drain)
  asm volatile("s_waitcnt lgkmcnt(0)" ::: "memory");
  __builtin_amdgcn_s_barrier();
}
__device__ __forceinline__ void bar_full(){   // drain everything, then barrier
  asm volatile("s_waitcnt vmcnt(0) lgkmcnt(0)" ::: "memory");
  __builtin_amdgcn_s_barrier();
}

// ---------------- RoPE tables: cos/sin [S][64] fp32 (+ work counter reset) ----------------
__global__ void k_tables(float* __restrict__ cosT, float* __restrict__ sinT){
  if (blockIdx.x == 0 && threadIdx.x == 0) g_work = 0u;
  int id = blockIdx.x*256 + threadIdx.x;      // S*64 = 131072 exact
  int p = id >> 6, i = id & 63;
  double f = (double)p * pow(10000.0, -(double)i/64.0);
  cosT[id] = (float)cos(f);
  sinT[id] = (float)sin(f);
}

// ---------------- fused fp32 -> bf16 converts (6 segments in one dispatch) ----------------
__global__ void k_cvt_all(const float* __restrict__ a0, bf16* __restrict__ o0,
                          const float* __restrict__ a1, bf16* __restrict__ o1,
                          const float* __restrict__ w0, bf16* __restrict__ q0,
                          const float* __restrict__ w1, bf16* __restrict__ q1,
                          const float* __restrict__ w2, bf16* __restrict__ q2,
                          const float* __restrict__ w3, bf16* __restrict__ q3){
  const float* src; bf16* dst; int n4;
  switch (blockIdx.y){
    case 0: src = a0; dst = o0; n4 = 2097152; break;
    case 1: src = a1; dst = o1; n4 = 2097152; break;
    case 2: src = w0; dst = q0; n4 = 1048576; break;
    case 3: src = w1; dst = q1; n4 = 1048576; break;
    case 4: src = w2; dst = q2; n4 = 1048576; break;
    default: src = w3; dst = q3; n4 = 1048576; break;
  }
  int i = blockIdx.x*256 + threadIdx.x;
  if (i >= n4) return;
  f32x4 v = *reinterpret_cast<const f32x4*>(src + (size_t)i*4);
  bf16x4 o;
  o[0]=(bf16)v[0]; o[1]=(bf16)v[1]; o[2]=(bf16)v[2]; o[3]=(bf16)v[3];
  *reinterpret_cast<bf16x4*>(dst + (size_t)i*4) = o;
}

// ---------------- hidden [B][S][HID] f32 -> hiddenT [B][HID][S] bf16 ----------------
__global__ __launch_bounds__(256) void k_transpose_cvt(const float* __restrict__ in, bf16* __restrict__ out){
  __shared__ bf16 t[64][72];
  const int tid = threadIdx.x;
  const int b = blockIdx.z, j0 = blockIdx.x*64, s0 = blockIdx.y*64;
  #pragma unroll
  for (int u0 = 0; u0 < 4; ++u0){
    int u = u0*256 + tid;
    int r = u >> 4, c4 = (u & 15)*4;
    f32x4 v = *reinterpret_cast<const f32x4*>(in + ((size_t)b*S_ + s0 + r)*HID_ + j0 + c4);
    bf16x4 o; o[0]=(bf16)v[0]; o[1]=(bf16)v[1]; o[2]=(bf16)v[2]; o[3]=(bf16)v[3];
    *reinterpret_cast<bf16x4*>(&t[r][c4]) = o;
  }
  __syncthreads();
  #pragma unroll
  for (int u0 = 0; u0 < 4; ++u0){
    int u = u0*256 + tid;
    int r = u >> 4, c4 = (u & 15)*4;    // r: j-local, c4: s-local
    bf16x4 o;
    o[0] = t[c4+0][r]; o[1] = t[c4+1][r]; o[2] = t[c4+2][r]; o[3] = t[c4+3][r];
    *reinterpret_cast<bf16x4*>(out + ((size_t)b*HID_ + j0 + r)*S_ + s0 + c4) = o;
  }
}

// ---------------- NT GEMM 128x128: C[M,N] = A[M,K] * B[N,K]^T, bf16 in, fp32 acc ----------------
// EPI 0: store bf16.  EPI 1: += (1-mask[row])*hid[row,col], store bf16 (batched).
// EPI 2: store fp32.  EPI 3: dual-output bf16 (col<2048 -> Cv, else -> hid-as-bf16).
template<int EPI>
__global__ __launch_bounds__(256) void k_gemm_nt(
    const bf16* __restrict__ A, const bf16* __restrict__ Bm, void* __restrict__ Cv,
    int Kd, size_t sAz, size_t sBz, size_t sCz, int N,
    const float* __restrict__ mask, const float* __restrict__ hid)
{
  const int tid = threadIdx.x;
  const int wid = tid >> 6, lane = tid & 63;
  const int g = lane >> 4, li = lane & 15;
  const int z = blockIdx.z;
  const int m0 = blockIdx.y*128, n0 = blockIdx.x*128;
  const int wm = wid >> 1, wn = wid & 1;
  const bf16* Ab = A + (size_t)z*sAz;
  const bf16* Bb = Bm + (size_t)z*sBz;

  __shared__ bf16 lA[128*64];
  __shared__ bf16 lB[128*64];

  f32x4 acc[4][4];
  #pragma unroll
  for (int i=0;i<4;++i)
    #pragma unroll
    for (int j=0;j<4;++j)
      acc[i][j] = {0.f,0.f,0.f,0.f};

  for (int k0 = 0; k0 < Kd; k0 += 64){
    #pragma unroll
    for (int j=0;j<4;++j){
      int ci = j*256 + tid;
      int r = ci >> 3, cb = ci & 7;     // 8 chunks of 16B per 64-elem row
      gload_lds16(Ab + (size_t)(m0 + r)*Kd + k0 + cb*8, (char*)lA + (j*256 + wid*64)*16);
      gload_lds16(Bb + (size_t)(n0 + r)*Kd + k0 + cb*8, (char*)lB + (j*256 + wid*64)*16);
    }
    __syncthreads();
    #pragma unroll
    for (int kk=0;kk<2;++kk){
      bf16x8 af[4], bfm[4];
      #pragma unroll
      for (int i=0;i<4;++i){
        af[i]  = *reinterpret_cast<const bf16x8*>(&lA[(wm*64 + i*16 + li)*64 + kk*32 + g*8]);
        bfm[i] = *reinterpret_cast<const bf16x8*>(&lB[(wn*64 + i*16 + li)*64 + kk*32 + g*8]);
      }
      #pragma unroll
      for (int i=0;i<4;++i)
        #pragma unroll
        for (int j=0;j<4;++j)
          acc[i][j] = mfma16(af[i], bfm[j], acc[i][j]);
    }
    __syncthreads();
  }

  #pragma unroll
  for (int i=0;i<4;++i){
    #pragma unroll
    for (int j=0;j<4;++j){
      #pragma unroll
      for (int v=0;v<4;++v){
        int row = m0 + wm*64 + i*16 + g*4 + v;   // C/D: col=lane&15, row=(lane>>4)*4+reg
        int col = n0 + wn*64 + j*16 + li;
        float x = acc[i][j][v];
        if (EPI == 1){
          x += (1.f - mask[z*S_ + row]) * hid[((size_t)z*S_ + row)*HID_ + col];
          ((bf16*)Cv)[(size_t)z*sCz + (size_t)row*N + col] = (bf16)x;
        } else if (EPI == 0){
          ((bf16*)Cv)[(size_t)row*N + col] = (bf16)x;
        } else if (EPI == 2){
          ((float*)Cv)[(size_t)row*N + col] = x;
        } else {  // EPI 3: dual output, block-uniform split at col 2048
          if (n0 < 2048) ((bf16*)Cv)[(size_t)row*2048 + col] = (bf16)x;
          else ((bf16*)(void*)hid)[(size_t)row*2048 + col - 2048] = (bf16)x;
        }
      }
    }
  }
}

// ---------------- NT GEMM 256x256: 8 waves, BK=64, double-buffered, issue-early ----------------
// Same EPI semantics as k_gemm_nt. Grid: (N/256, M/256, z). 512 threads.
template<int EPI>
__global__ __launch_bounds__(512,2) void k_gemm256(
    const bf16* __restrict__ A, const bf16* __restrict__ Bm, void* __restrict__ Cv,
    int Kd, size_t sAz, size_t sBz, size_t sCz, int N,
    const float* __restrict__ mask, const float* __restrict__ hid)
{
  const int tid = threadIdx.x;
  const int wid = tid >> 6, lane = tid & 63;
  const int g = lane >> 4, li = lane & 15;
  const int wm = wid >> 2, wn = wid & 3;      // wave grid 2 (M) x 4 (N)
  const int z = blockIdx.z;
  const int m0 = blockIdx.y*256, n0 = blockIdx.x*256;
  const bf16* Ab = A + (size_t)z*sAz + (size_t)m0*Kd;
  const bf16* Bb = Bm + (size_t)z*sBz + (size_t)n0*Kd;

  __shared__ bf16 lA[2][256*64];   // 128 KiB total
  __shared__ bf16 lB[2][256*64];

  const int rr0 = tid >> 3, cc = tid & 7;
  const int rr1 = rr0 + 64;
  const int cx0 = cc ^ (rr0 & 7);
  const int cx1 = cc ^ (rr1 & 7);

  f32x4 acc[8][4];
  #pragma unroll
  for (int i=0;i<8;++i)
    #pragma unroll
    for (int j=0;j<4;++j) acc[i][j] = {0.f,0.f,0.f,0.f};

  auto stage = [&](int buf, int kt, int matsel, int half){
    const bf16* s = matsel ? Bb : Ab;
    char* dbase = (char*)(matsel ? lB[buf] : lA[buf]) + half*16384;
    gload_lds16(s + (size_t)(half*128 + rr0)*Kd + kt*64 + cx0*8, dbase + (wid*64)*16);
    gload_lds16(s + (size_t)(half*128 + rr1)*Kd + kt*64 + cx1*8, dbase + (512 + wid*64)*16);
  };
  auto rdA = [&](int buf, int i, int kh){
    int row = wm*128 + i*16 + li;
    return *reinterpret_cast<const bf16x8*>((const char*)lA[buf] + row*128 + (((kh*4 + g) ^ (row & 7))*16));
  };
  auto rdB = [&](int buf, int j, int kh){
    int row = wn*64 + j*16 + li;
    return *reinterpret_cast<const bf16x8*>((const char*)lB[buf] + row*128 + (((kh*4 + g) ^ (row & 7))*16));
  };

  const int NT = Kd >> 6;
  stage(0,0,0,0); stage(0,0,0,1); stage(0,0,1,0); stage(0,0,1,1);
  __syncthreads();

  int cur = 0;
  for (int kt = 0; kt < NT; ++kt){
    const bool more = (kt+1 < NT);
    bf16x8 af[4], bfr[4];

    if (more){
      stage(cur^1, kt+1, 0, 0); stage(cur^1, kt+1, 0, 1);
      stage(cur^1, kt+1, 1, 0); stage(cur^1, kt+1, 1, 1);
    }
    #pragma unroll
    for (int i=0;i<4;++i) af[i] = rdA(cur, i, 0);
    #pragma unroll
    for (int j=0;j<4;++j) bfr[j] = rdB(cur, j, 0);
    __builtin_amdgcn_s_setprio(1);
    #pragma unroll
    for (int i=0;i<4;++i)
      #pragma unroll
      for (int j=0;j<4;++j) acc[i][j] = mfma16(af[i], bfr[j], acc[i][j]);
    __builtin_amdgcn_s_setprio(0);
    __builtin_amdgcn_s_barrier();

    #pragma unroll
    for (int i=0;i<4;++i) af[i] = rdA(cur, i+4, 0);
    __builtin_amdgcn_s_setprio(1);
    #pragma unroll
    for (int i=0;i<4;++i)
      #pragma unroll
      for (int j=0;j<4;++j) acc[i+4][j] = mfma16(af[i], bfr[j], acc[i+4][j]);
    __builtin_amdgcn_s_setprio(0);
    __builtin_amdgcn_s_barrier();

    #pragma unroll
    for (int i=0;i<4;++i) af[i] = rdA(cur, i, 1);
    #pragma unroll
    for (int j=0;j<4;++j) bfr[j] = rdB(cur, j, 1);
    __builtin_amdgcn_s_setprio(1);
    #pragma unroll
    for (int i=0;i<4;++i)
      #pragma unroll
      for (int j=0;j<4;++j) acc[i][j] = mfma16(af[i], bfr[j], acc[i][j]);
    __builtin_amdgcn_s_setprio(0);
    __builtin_amdgcn_s_barrier();

    #pragma unroll
    for (int i=0;i<4;++i) af[i] = rdA(cur, i+4, 1);
    __builtin_amdgcn_s_setprio(1);
    #pragma unroll
    for (int i=0;i<4;++i)
      #pragma unroll
      for (int j=0;j<4;++j) acc[i+4][j] = mfma16(af[i], bfr[j], acc[i+4][j]);
    __builtin_amdgcn_s_setprio(0);

    __syncthreads();
    cur ^= 1;
  }

  #pragma unroll
  for (int i=0;i<8;++i){
    #pragma unroll
    for (int j=0;j<4;++j){
      #pragma unroll
      for (int v=0;v<4;++v){
        int row = m0 + wm*128 + i*16 + g*4 + v;
        int col = n0 + wn*64 + j*16 + li;
        float x = acc[i][j][v];
        if (EPI == 1){
          x += (1.f - mask[z*S_ + row]) * hid[((size_t)z*S_ + row)*HID_ + col];
          ((bf16*)Cv)[(size_t)z*sCz + (size_t)row*N + col] = (bf16)x;
        } else if (EPI == 0){
          ((bf16*)Cv)[(size_t)row*N + col] = (bf16)x;
        } else if (EPI == 2){
          ((float*)Cv)[(size_t)row*N + col] = x;
        } else {
          if (n0 < 2048) ((bf16*)Cv)[(size_t)row*2048 + col] = (bf16)x;
          else ((bf16*)(void*)hid)[(size_t)row*2048 + col - 2048] = (bf16)x;
        }
      }
    }
  }
}

// ---------------- RoPE in place on [B,S,H,D] bf16 ----------------
__global__ void k_rope(bf16* __restrict__ X, const float* __restrict__ cosT,
                       const float* __restrict__ sinT, const int* __restrict__ pos){
  int id = blockIdx.x*256 + threadIdx.x;   // B*S*H*16 = 1048576 exact
  int d4 = (id & 15)*4;
  int h  = (id >> 4) & 15;
  int s  = (id >> 8) & 2047;
  int b  = id >> 19;
  int p = pos ? pos[b*S_ + s] : s;
  size_t base = (((size_t)b*S_ + s)*H_ + h)*D_ + d4;
  f32x4 c  = *reinterpret_cast<const f32x4*>(cosT + (size_t)p*64 + d4);
  f32x4 sn = *reinterpret_cast<const f32x4*>(sinT + (size_t)p*64 + d4);
  bf16x4 x1 = *reinterpret_cast<bf16x4*>(X + base);
  bf16x4 x2 = *reinterpret_cast<bf16x4*>(X + base + 64);
  bf16x4 o1, o2;
  #pragma unroll
  for (int i=0;i<4;++i){
    float a = (float)x1[i], bb = (float)x2[i];
    o1[i] = (bf16)(a*c[i] - bb*sn[i]);
    o2[i] = (bf16)(bb*c[i] + a*sn[i]);
  }
  *reinterpret_cast<bf16x4*>(X + base) = o1;
  *reinterpret_cast<bf16x4*>(X + base + 64) = o2;
}

// ---------------- causal flash attention: persistent, 8-wave 256-row q-tiles ----------------
// 256 persistent blocks (1/CU), 8 waves x 32 q-rows = 256-row q-tiles, kv tile 64.
// 384 items, heavy-first; qx>=4 split into kv-halves (bf16 partials + fp32 m/l).
__global__ __launch_bounds__(512,2) void k_flash(const bf16* __restrict__ Q, const bf16* __restrict__ K,
                                                 const bf16* __restrict__ V, bf16* __restrict__ O,
                                                 bf16* __restrict__ OPb, float* __restrict__ ML)
{
  const int tid = threadIdx.x;
  const int wid = tid >> 6, lane = tid & 63;
  const int g = lane >> 4, li = lane & 15;

  __shared__ bf16 Klds[2][64*128];    // double-buffered K, source chunk-XOR swizzled (32 KB)
  __shared__ char VtB[128*128];       // V^T [d][kv] bf16, XOR-swizzled 16B chunks (16 KB)
  __shared__ bf16 Plds[8][32*72];     // per-wave P (36 KB)
  __shared__ int s_item;

  const int dc = tid & 15, kvp = tid >> 4;   // V-staging role: kv rows [2*kvp, 2*kvp+1], d-chunk dc

  for (;;) {
    if (tid == 0) s_item = (int)atomicAdd(&g_work, 1u);
    __syncthreads();
    const int w = s_item;
    if (w >= 384) return;

    // item decode (heavy-first): units = t1-t0
    int qx, bh, part, t0, t1;
    if (w < 64)       { qx = 7; int u = w;       bh = u>>1; part = u&1; t0 = part?16:0; t1 = part?32:16; }
    else if (w < 96)  { qx = 3; bh = w-64;  part = -1; t0 = 0; t1 = 16; }
    else if (w < 160) { qx = 6; int u = w-96;  bh = u>>1; part = u&1; t0 = part?14:0; t1 = part?28:14; }
    else if (w < 224) { qx = 5; int u = w-160; bh = u>>1; part = u&1; t0 = part?12:0; t1 = part?24:12; }
    else if (w < 256) { qx = 2; bh = w-224; part = -1; t0 = 0; t1 = 12; }
    else if (w < 320) { qx = 4; int u = w-256; bh = u>>1; part = u&1; t0 = part?10:0; t1 = part?20:10; }
    else if (w < 352) { qx = 1; bh = w-320; part = -1; t0 = 0; t1 = 8; }
    else              { qx = 0; bh = w-352; part = -1; t0 = 0; t1 = 4; }

    const int qb = qx * 256;
    const size_t headoff = ((size_t)(bh >> 4)*S_*H_ + (bh & 15))*D_;
    const bf16* Kh = K + headoff;
    const u16*  Vh = (const u16*)(V + headoff);

    // Q fragments: 2 row-blocks of 16 per wave (32 rows/wave)
    bf16x8 qf[2][4];
    #pragma unroll
    for (int rb=0;rb<2;++rb){
      const bf16* Qp = Q + headoff + (size_t)(qb + wid*32 + rb*16 + li)*H_*D_;
      #pragma unroll
      for (int kc=0;kc<4;++kc)
        qf[rb][kc] = *reinterpret_cast<const bf16x8*>(Qp + kc*32 + g*8);
    }

    float mrun[2][4], lrun[2][4];
    f32x4 acc[2][8];
    #pragma unroll
    for (int rb=0;rb<2;++rb){
      #pragma unroll
      for (int v=0;v<4;++v){ mrun[rb][v] = -1e30f; lrun[rb][v] = 0.f; }
      #pragma unroll
      for (int fn=0;fn<8;++fn) acc[rb][fn] = {0.f,0.f,0.f,0.f};
    }

    u16x8 vp[2];
    auto stageK = [&](int buf, int t){
      #pragma unroll
      for (int j=0;j<2;++j){
        int ci = j*512 + tid;
        int r = ci >> 4, cb = ci & 15;
        const char* src = (const char*)(Kh + (size_t)(t*64 + r)*H_*D_) + ((cb ^ (r & 7)) * 16);
        gload_lds16(src, (char*)Klds[buf] + (j*512 + wid*64)*16);
      }
    };
    auto loadV = [&](int t){
      const u16* sp = Vh + (size_t)(t*64 + kvp*2)*H_*D_ + dc*8;
      vp[0] = *reinterpret_cast<const u16x8*>(sp);
      vp[1] = *reinterpret_cast<const u16x8*>(sp + H_*D_);
    };
    auto writeVtB = [&](){
      #pragma unroll
      for (int e=0;e<8;++e){
        int r = dc*8 + e;
        int swz = (r ^ (r >> 3)) & 7;
        int addr = r*128 + (((kvp >> 2) ^ swz) << 4) + ((kvp << 2) & 12);
        *reinterpret_cast<uint32_t*>(VtB + addr) =
            (uint32_t)vp[0][e] | ((uint32_t)vp[1][e] << 16);
      }
    };

    // prologue: stage tile t0
    stageK(0, t0);
    loadV(t0);
    writeVtB();
    bar_full();

    int cur = 0;
    for (int t=t0; t<t1; ++t){
      const bool more = (t+1 < t1);
      if (more){ stageK(cur^1, t+1); loadV(t+1); }   // overlapped with this tile's compute

      // ---- QK^T: wave computes 32 rows x 64 cols ----
      f32x4 sc[2][4];
      #pragma unroll
      for (int fc=0;fc<4;++fc){
        int r = fc*16 + li;
        bf16x8 kf[4];
        #pragma unroll
        for (int kc=0;kc<4;++kc)
          kf[kc] = *reinterpret_cast<const bf16x8*>((const char*)Klds[cur] + r*256 + (((4*kc + g) ^ (r & 7))*16));
        __builtin_amdgcn_s_setprio(1);
        #pragma unroll
        for (int rb=0;rb<2;++rb){
          f32x4 s = {0.f,0.f,0.f,0.f};
          #pragma unroll
          for (int kc=0;kc<4;++kc)
            s = mfma16(qf[rb][kc], kf[kc], s);
          sc[rb][fc] = s;
        }
        __builtin_amdgcn_s_setprio(0);
      }

      // ---- scale (+ causal mask on diagonal tiles t in [4qx, 4qx+4)) ----
      const float scale = 0.08838834764831845f;  // 1/sqrt(128)
      const int c0 = t*64;
      if (t >= 4*qx){
        #pragma unroll
        for (int rb=0;rb<2;++rb){
          const int rowg = qb + wid*32 + rb*16 + g*4;
          #pragma unroll
          for (int fc=0;fc<4;++fc){
            int col = c0 + fc*16 + li;
            #pragma unroll
            for (int v=0;v<4;++v){
              float s = sc[rb][fc][v] * scale;
              sc[rb][fc][v] = (col > rowg + v) ? -1e30f : s;
            }
          }
        }
      } else {
        #pragma unroll
        for (int rb=0;rb<2;++rb)
          #pragma unroll
          for (int fc=0;fc<4;++fc)
            #pragma unroll
            for (int v=0;v<4;++v)
              sc[rb][fc][v] *= scale;
      }

      // ---- online softmax with defer-max (THR=8), per row-block ----
      #pragma unroll
      for (int rb=0;rb<2;++rb){
        float tm[4];
        #pragma unroll
        for (int v=0;v<4;++v){
          float m2 = fmaxf(fmaxf(sc[rb][0][v], sc[rb][1][v]), fmaxf(sc[rb][2][v], sc[rb][3][v]));
          m2 = fmaxf(m2, __shfl_xor(m2, 1));
          m2 = fmaxf(m2, __shfl_xor(m2, 2));
          m2 = fmaxf(m2, __shfl_xor(m2, 4));
          m2 = fmaxf(m2, __shfl_xor(m2, 8));
          tm[v] = m2;
        }
        bool need = false;
        #pragma unroll
        for (int v=0;v<4;++v) need = need || (tm[v] > mrun[rb][v] + 8.f);
        if (__any(need)){
          float al[4];
          #pragma unroll
          for (int v=0;v<4;++v){
            float mnew = fmaxf(mrun[rb][v], tm[v]);
            al[v] = __expf(mrun[rb][v] - mnew);
            mrun[rb][v] = mnew;
            lrun[rb][v] *= al[v];
          }
          #pragma unroll
          for (int fn=0;fn<8;++fn)
            #pragma unroll
            for (int v=0;v<4;++v) acc[rb][fn][v] *= al[v];
        }
        float rs[4] = {0.f,0.f,0.f,0.f};
        #pragma unroll
        for (int fc=0;fc<4;++fc){
          #pragma unroll
          for (int v=0;v<4;++v){
            float p = __expf(sc[rb][fc][v] - mrun[rb][v]);
            rs[v] += p;
            Plds[wid][(rb*16 + g*4 + v)*72 + fc*16 + li] = (bf16)p;
          }
        }
        #pragma unroll
        for (int v=0;v<4;++v){
          float r = rs[v];
          r += __shfl_xor(r, 1); r += __shfl_xor(r, 2);
          r += __shfl_xor(r, 4); r += __shfl_xor(r, 8);
          lrun[rb][v] += r;
        }
      }

      // ---- PV: O[32 x 128] += P[32 x 64] * V[64 x 128] ----
      bf16x8 pa[2][2];
      #pragma unroll
      for (int rb=0;rb<2;++rb)
        #pragma unroll
        for (int kc=0;kc<2;++kc)
          pa[rb][kc] = *reinterpret_cast<const bf16x8*>(&Plds[wid][(rb*16 + li)*72 + kc*32 + g*8]);
      #pragma unroll
      for (int fn=0;fn<8;++fn){
        int r = fn*16 + li;
        int swz = (r ^ (r >> 3)) & 7;
        bf16x8 bv[2];
        #pragma unroll
        for (int kc=0;kc<2;++kc)
          bv[kc] = *reinterpret_cast<const bf16x8*>(VtB + r*128 + (((kc*4 + g) ^ swz) << 4));
        __builtin_amdgcn_s_setprio(1);
        #pragma unroll
        for (int rb=0;rb<2;++rb)
          #pragma unroll
          for (int kc=0;kc<2;++kc)
            acc[rb][fn] = mfma16(pa[rb][kc], bv[kc], acc[rb][fn]);
        __builtin_amdgcn_s_setprio(0);
      }

      if (more){
        bar_lgkm();        // all waves done reading VtB; no vmcnt drain
        writeVtB();        // commit next tile's V
      }
      bar_full();          // drains K-DMA issued ~1 tile ago + V ds_writes
      cur ^= 1;
    }

    // ---- epilogue ----
    if (part < 0){
      #pragma unroll
      for (int rb=0;rb<2;++rb){
        #pragma unroll
        for (int v=0;v<4;++v){
          float inv = 1.f / lrun[rb][v];
          int row = qb + wid*32 + rb*16 + g*4 + v;
          bf16* dst = O + headoff + (size_t)row*H_*D_ + li;
          #pragma unroll
          for (int fn=0;fn<8;++fn)
            dst[fn*16] = (bf16)(acc[rb][fn][v] * inv);
        }
      }
    } else {
      const int sidx = ((qx-4)<<6) + (bh<<1) + part;     // [0,256)
      bf16* Od = OPb + (size_t)sidx*256*128;
      float* MLd = ML + (size_t)sidx*512;
      #pragma unroll
      for (int rb=0;rb<2;++rb){
        #pragma unroll
        for (int v=0;v<4;++v){
          float inv = 1.f / lrun[rb][v];
          int rl = wid*32 + rb*16 + g*4 + v;
          #pragma unroll
          for (int fn=0;fn<8;++fn)
            Od[rl*128 + fn*16 + li] = (bf16)(acc[rb][fn][v] * inv);   // normalized partial
          if (li == 0){
            MLd[rl*2 + 0] = mrun[rb][v];
            MLd[rl*2 + 1] = lrun[rb][v];
          }
        }
      }
    }
  }
}

// ---------------- merge split-kv partials into O ----------------
__global__ __launch_bounds__(256) void k_merge(const bf16* __restrict__ OPb, const float* __restrict__ ML,
                                               bf16* __restrict__ O){
  const int gid = blockIdx.x;         // 128 groups: qx 4..7 x 32 bh
  const int qx = 4 + (gid >> 5);
  const int bh = gid & 31;
  const int s0 = ((qx-4)<<6) + (bh<<1), s1 = s0 + 1;
  const int b = bh >> 4, h = bh & 15;
  const int qb = qx * 256;
  const int row = threadIdx.x;        // 0..255

  float m0 = ML[(size_t)s0*512 + row*2], l0 = ML[(size_t)s0*512 + row*2 + 1];
  float m1 = ML[(size_t)s1*512 + row*2], l1 = ML[(size_t)s1*512 + row*2 + 1];
  float mm = fmaxf(m0, m1);
  float w0 = l0 * __expf(m0 - mm), w1 = l1 * __expf(m1 - mm);
  float inv = 1.f / (w0 + w1);
  w0 *= inv; w1 *= inv;
  const bf16* r0 = OPb + ((size_t)s0*256 + row)*128;
  const bf16* r1 = OPb + ((size_t)s1*256 + row)*128;
  bf16* dst = O + (((size_t)b*S_ + qb + row)*H_ + h)*D_;
  #pragma unroll
  for (int c=0; c<128; c+=8){
    bf16x8 a = *reinterpret_cast<const bf16x8*>(r0 + c);
    bf16x8 bq = *reinterpret_cast<const bf16x8*>(r1 + c);
    bf16x8 o;
    #pragma unroll
    for (int i=0;i<8;++i) o[i] = (bf16)((float)a[i]*w0 + (float)bq[i]*w1);
    *reinterpret_cast<bf16x8*>(dst + c) = o;
  }
}

extern "C" void kernel_launch(void* const* d_in, const int* in_sizes, int n_in,
                              void* d_out, int out_size, void* d_ws, size_t ws_size,
                              hipStream_t stream)
{
  (void)in_sizes; (void)n_in; (void)out_size; (void)ws_size;
  const float* hid   = (const float*)d_in[0];
  const float* smask = (const float*)d_in[1];
  const float* samat = (const float*)d_in[2];
  const int*   pos   = (const int*)d_in[4];
  const float* Wq = (const float*)d_in[5];
  const float* Wk = (const float*)d_in[6];
  const float* Wv = (const float*)d_in[7];
  const float* Wo = (const float*)d_in[8];
  float* out = (float*)d_out;
  char* ws = (char*)d_ws;

  const size_t SZ_TAB = (size_t)S_*64*4;        // 512 KB per table
  const size_t SZ_BSH = (size_t)B_*S_*HID_*2;   // 16 MB bf16 [B,S,HID]
  float* cosT = (float*)(ws);
  float* sinT = (float*)(ws + SZ_TAB);
  bf16* buf1 = (bf16*)(ws + 2*SZ_TAB);                 // hidden_bf -> v
  bf16* buf2 = (bf16*)(ws + 2*SZ_TAB + 1*SZ_BSH);      // hiddenT  -> k
  bf16* buf3 = (bf16*)(ws + 2*SZ_TAB + 2*SZ_BSH);      // samat_bf -> q
  bf16* buf4 = (bf16*)(ws + 2*SZ_TAB + 3*SZ_BSH);      // hm -> attention O
  bf16* Wqb = (bf16*)(ws + 2*SZ_TAB + 4*SZ_BSH);
  bf16* Wkb = Wqb + (size_t)HID_*HID_;
  bf16* Wvb = Wkb + (size_t)HID_*HID_;
  bf16* Wob = Wvb + (size_t)HID_*HID_;
  // flash split partials alias the (dead-after-GEMM) Wq/Wk/Wv region:
  // 256 partials x 256x128 bf16 (16 MB) + m/l fp32 (0.5 MB) <= 24 MB
  bf16* OPb = Wqb;
  float* ML = (float*)(Wqb + (size_t)256*256*128);

  k_tables<<<512,256,0,stream>>>(cosT, sinT);
  k_cvt_all<<<dim3(8192,6),256,0,stream>>>(hid, buf1, samat, buf3,
                                           Wq, Wqb, Wk, Wkb, Wv, Wvb, Wo, Wob);
  k_transpose_cvt<<<dim3(32,32,2),256,0,stream>>>(hid, buf2);

  const size_t sBat = (size_t)S_*HID_;
  // G1: hm = sum_attn_mask @ hidden + (1-m)*hidden   (batched)
  k_gemm_nt<1><<<dim3(16,16,2),256,0,stream>>>(buf3, buf2, buf4, 2048, sBat, sBat, sBat, 2048, smask, hid);
  // G2: q = hidden_bf @ Wq^T
  k_gemm_nt<0><<<dim3(16,32,1),256,0,stream>>>(buf1, Wqb, buf3, 2048, 0,0,0, 2048, nullptr, nullptr);
  k_rope<<<4096,256,0,stream>>>(buf3, cosT, sinT, pos);
  // G3+G4 fused: [k|v] = hm @ [Wk|Wv]^T  (256^2 8-wave kernel, dual output)
  k_gemm256<3><<<dim3(16,16,1),512,0,stream>>>(buf4, Wkb, buf2, 2048, 0,0,0, 2048, nullptr, (const float*)buf1);
  k_rope<<<4096,256,0,stream>>>(buf2, cosT, sinT, nullptr);
  // attention: O -> buf4 (hm dead); split partials -> OPb/ML
  k_flash<<<dim3(256),512,0,stream>>>(buf3, buf2, buf1, buf4, OPb, ML);
  k_merge<<<dim3(128),256,0,stream>>>(OPb, ML, buf4);
  // G5: out = O @ Wo^T -> fp32
  k_gemm_nt<2><<<dim3(16,32,1),256,0,stream>>>(buf4, Wob, out, 2048, 0,0,0, 2048, nullptr, nullptr);
}